// Round 3
// baseline (512.101 us; speedup 1.0000x reference)
//
#include <hip/hip_runtime.h>

typedef __bf16 bf16_t;
typedef bf16_t bf16x8 __attribute__((ext_vector_type(8)));
typedef float  floatx4 __attribute__((ext_vector_type(4)));
typedef unsigned int uint;

constexpr int Mdim = 2048;
constexpr int Kdim = 4096;
constexpr int Ndim = 11008;
constexpr int NPK  = Ndim / 8;     // 1376 packed words per k-row
constexpr int SQ   = 68;           // qbuf stride (words)
// fused-fallback tile params
constexpr int BM = 128, BN = 128, BK = 64;
constexpr int SA = 72, SB = 72;

#define GLOAD_LDS16(g, l) \
    __builtin_amdgcn_global_load_lds((const __attribute__((address_space(1))) void*)(g), \
                                     (__attribute__((address_space(3))) void*)(l), 16, 0, 0)
#define MFMA(a, b, c) __builtin_amdgcn_mfma_f32_16x16x32_bf16((a), (b), (c), 0, 0, 0)
#define BAR()    __builtin_amdgcn_s_barrier()
#define LGKM0()  asm volatile("s_waitcnt lgkmcnt(0)" ::: "memory")
#define VMCNT2() asm volatile("s_waitcnt vmcnt(2)" ::: "memory")
#define PRIO1()  __builtin_amdgcn_s_setprio(1)
#define PRIO0()  __builtin_amdgcn_s_setprio(0)

__global__ void xcast_kernel(const float* __restrict__ x, bf16_t* __restrict__ xb)
{
    const int i = (blockIdx.x * 256 + threadIdx.x) * 8;
    const float4 a = *(const float4*)(x + i);
    const float4 b = *(const float4*)(x + i + 4);
    bf16x8 v;
    v[0] = (bf16_t)a.x; v[1] = (bf16_t)a.y; v[2] = (bf16_t)a.z; v[3] = (bf16_t)a.w;
    v[4] = (bf16_t)b.x; v[5] = (bf16_t)b.y; v[6] = (bf16_t)b.z; v[7] = (bf16_t)b.w;
    *(bf16x8*)(xb + i) = v;
}

// ---------------------------------------------------------------------------
// One-shot W dequant: qweight [k][c] int4-packed -> wt [n][k] bf16 (W^T).
// Write-coalesced layout: 8 consecutive lanes cover one row's 64 k (128 B
// contiguous per 8 lanes). qbuf reads are wave-broadcast (same cc per wave).
// ---------------------------------------------------------------------------
__global__ __launch_bounds__(256, 4)
void wdeq_kernel(const uint* __restrict__ qweight, const uint* __restrict__ qzeros,
                 const float* __restrict__ scales, bf16_t* __restrict__ wt)
{
    __shared__ uint qbuf[16 * SQ];
    const int t  = threadIdx.x;
    const int n0 = blockIdx.x * 128;
    const int k0 = blockIdx.y * 64;
    const int c0 = n0 >> 3;
    const int g  = k0 >> 7;

    // stage 64k x 16c packed words, transposed to qbuf[c][k]
    const int qk  = t >> 2;
    const int qc4 = (t & 3) * 4;
    const uint4 w4 = *(const uint4*)(qweight + (size_t)(k0 + qk) * NPK + c0 + qc4);
    qbuf[(qc4 + 0) * SQ + qk] = w4.x;
    qbuf[(qc4 + 1) * SQ + qk] = w4.y;
    qbuf[(qc4 + 2) * SQ + qk] = w4.z;
    qbuf[(qc4 + 3) * SQ + qk] = w4.w;
    __syncthreads();

    const int kcol = t & 7;            // k-word block: words kcol*8 .. +7
    const int nr   = t >> 3;           // 0..31
    const int jsh  = (nr & 7) * 4;     // invariant across j (row += 32)
#pragma unroll
    for (int j = 0; j < 4; ++j) {
        const int row = nr + j * 32;          // 0..127
        const int cc  = row >> 3;             // 0..15
        const uint  zw = qzeros[(size_t)g * NPK + c0 + cc];
        const float s  = scales[(size_t)g * Ndim + n0 + row];
        const float zs = (float)((zw >> jsh) & 15u) * s;
        const uint* qrow = &qbuf[cc * SQ + kcol * 8];
        const uint4 qa = *(const uint4*)(qrow);
        const uint4 qb = *(const uint4*)(qrow + 4);
        bf16x8 v;
        v[0] = (bf16_t)((float)((qa.x >> jsh) & 15u) * s - zs);
        v[1] = (bf16_t)((float)((qa.y >> jsh) & 15u) * s - zs);
        v[2] = (bf16_t)((float)((qa.z >> jsh) & 15u) * s - zs);
        v[3] = (bf16_t)((float)((qa.w >> jsh) & 15u) * s - zs);
        v[4] = (bf16_t)((float)((qb.x >> jsh) & 15u) * s - zs);
        v[5] = (bf16_t)((float)((qb.y >> jsh) & 15u) * s - zs);
        v[6] = (bf16_t)((float)((qb.z >> jsh) & 15u) * s - zs);
        v[7] = (bf16_t)((float)((qb.w >> jsh) & 15u) * s - zs);
        *(bf16x8*)(wt + (size_t)(n0 + row) * Kdim + k0 + kcol * 8) = v;
    }
}

// ---------------------------------------------------------------------------
// Phased bf16 GEMM with K-SPLIT waves.
// BM=256, BN=128, BK=64. 512 threads = 8 waves as 2M x 2N x 2K.
// Wave tile 128(m) x 64(n) on k-slice wk (32 of each 64-k tile).
// Per wave per K-tile: 8 A-frag + 4 B-frag ds_read_b128, 32 MFMA
//   -> LDS:MFMA cycle ratio 0.93 (was 1.55 with the 128x32 wave tile).
// Staging/vmcnt ledger identical to the round-2 verified schedule.
// Epilogue: wk-pair acc exchange through LDS, then store.
// ---------------------------------------------------------------------------
__global__ __launch_bounds__(512, 2)
void gemm8_kernel(const bf16_t* __restrict__ xb, const bf16_t* __restrict__ wt,
                  const float* __restrict__ bias, float* __restrict__ out)
{
    __shared__ bf16_t As[2 * 16384];   // 64 KiB  [p][h][128][64]
    __shared__ bf16_t Bs[2 * 8192];    // 32 KiB  [p][128][64]

    const int t    = threadIdx.x;
    const int w    = t >> 6;
    const int lane = t & 63;
    const int quad = lane >> 4;
    const int l16  = lane & 15;
    const int wm   = w >> 2;           // 0..1  (m half)
    const int wn   = (w >> 1) & 1;     // 0..1  (n half)
    const int wk   = w & 1;            // 0..1  (k slice)
    const int w64  = w * 64;

    // T1: XCD-aware remap (688 = 8*86, bijective).
    const int flat = blockIdx.y * 86 + blockIdx.x;
    const int nf   = (flat & 7) * 86 + (flat >> 3);
    const int m0   = (nf / 86) * 256;
    const int n0   = (nf % 86) * 128;

    auto stageA = [&](int T, int h) {
        const int p  = T & 1;
        const int Tk = (T & 63) * 64;
#pragma unroll
        for (int l = 0; l < 2; ++l) {
            const int idx = l * 512 + w64 + lane;
            const int r   = idx >> 3;
            const int bc  = (idx & 7) ^ (r & 7);
            GLOAD_LDS16(xb + (size_t)(m0 + h * 128 + r) * Kdim + Tk + bc * 8,
                        As + (p * 16384 + h * 8192 + (l * 512 + w64) * 8));
        }
    };
    auto stageB = [&](int T) {
        const int p  = T & 1;
        const int Tk = (T & 63) * 64;
#pragma unroll
        for (int l = 0; l < 2; ++l) {
            const int idx = l * 512 + w64 + lane;
            const int r   = idx >> 3;
            const int bc  = (idx & 7) ^ (r & 7);
            GLOAD_LDS16(wt + (size_t)(n0 + r) * Kdim + Tk + bc * 8,
                        Bs + (p * 8192 + (l * 512 + w64) * 8));
        }
    };
    auto lda = [&](int p, int mt) -> bf16x8 {
        const int r = mt * 16 + l16;
        return *(const bf16x8*)(As + p * 16384 + wm * 8192 + r * 64 +
                                ((wk * 4 + quad) ^ (l16 & 7)) * 8);
    };
    auto ldb = [&](int p, int nt) -> bf16x8 {
        const int r = wn * 64 + nt * 16 + l16;
        return *(const bf16x8*)(Bs + p * 8192 + r * 64 +
                                ((wk * 4 + quad) ^ (l16 & 7)) * 8);
    };

    floatx4 acc[8][4];
#pragma unroll
    for (int i = 0; i < 8; ++i)
#pragma unroll
        for (int j = 0; j < 4; ++j)
            acc[i][j] = (floatx4){0.f, 0.f, 0.f, 0.f};

    // prologue: tile0 A+B, tile1 B; leave tile1's B (newest 2) outstanding
    stageA(0, 0); stageA(0, 1); stageB(0); stageB(1);
    VMCNT2(); BAR();

    bf16x8 av[4], bb[4];

#define MFMA16(G)                                                              \
    PRIO1();                                                                   \
    _Pragma("unroll") for (int mt = 0; mt < 4; ++mt)                           \
        _Pragma("unroll") for (int nt = 0; nt < 4; ++nt)                       \
            acc[(G)*4 + mt][nt] = MFMA(av[mt], bb[nt], acc[(G)*4 + mt][nt]);   \
    PRIO0();

    for (int i = 0; i < 32; ++i) {
        // ---- phase 1: buf0, m-frags 0-3 ----
        bb[0] = ldb(0, 0); bb[1] = ldb(0, 1); bb[2] = ldb(0, 2); bb[3] = ldb(0, 3);
        av[0] = lda(0, 0); av[1] = lda(0, 1); av[2] = lda(0, 2); av[3] = lda(0, 3);
        stageA(2 * i + 1, 0); stageA(2 * i + 1, 1);
        BAR(); LGKM0();
        MFMA16(0);
        BAR();

        // ---- phase 2: buf0, m-frags 4-7 (bb reused) ----
        av[0] = lda(0, 4); av[1] = lda(0, 5); av[2] = lda(0, 6); av[3] = lda(0, 7);
        stageB(2 * i + 2);
        VMCNT2();
        BAR(); LGKM0();
        MFMA16(1);
        BAR();

        // ---- phase 3: buf1, m-frags 0-3 ----
        bb[0] = ldb(1, 0); bb[1] = ldb(1, 1); bb[2] = ldb(1, 2); bb[3] = ldb(1, 3);
        av[0] = lda(1, 0); av[1] = lda(1, 1); av[2] = lda(1, 2); av[3] = lda(1, 3);
        stageA(2 * i + 2, 0); stageA(2 * i + 2, 1);
        BAR(); LGKM0();
        MFMA16(0);
        BAR();

        // ---- phase 4: buf1, m-frags 4-7 ----
        av[0] = lda(1, 4); av[1] = lda(1, 5); av[2] = lda(1, 6); av[3] = lda(1, 7);
        stageB(2 * i + 3);
        VMCNT2();
        BAR(); LGKM0();
        MFMA16(1);
        BAR();
    }
#undef MFMA16

    // ---- cross-k reduction: partner wave = w^1 (same wm,wn, other wk).
    // wk0 keeps m-frags 0-3 (sends 4-7); wk1 keeps 4-7 (sends 0-3).
    // Outstanding tail stages target Bs only (A drained at last VMCNT2),
    // so As is safe to reuse as the exchange buffer.
    {
        float* exf = (float*)As;           // 8 waves * 2048 floats = 64 KiB
        const int pw = w ^ 1;
#pragma unroll
        for (int c = 0; c < 2; ++c) {
            const int sbase = (wk ? 0 : 4) + c * 2;   // frags sent
            const int kbase = (wk ? 4 : 0) + c * 2;   // frags kept/received
#pragma unroll
            for (int q = 0; q < 2; ++q)
#pragma unroll
                for (int nt = 0; nt < 4; ++nt)
                    *(floatx4*)(exf + w * 2048 + ((q * 4 + nt) * 64 + lane) * 4) =
                        acc[sbase + q][nt];
            __syncthreads();
#pragma unroll
            for (int q = 0; q < 2; ++q)
#pragma unroll
                for (int nt = 0; nt < 4; ++nt)
                    acc[kbase + q][nt] += *(const floatx4*)(exf + pw * 2048 +
                                            ((q * 4 + nt) * 64 + lane) * 4);
            __syncthreads();
        }
    }

    // ---- store: wave stores its kept 4 m-frags ----
    const int mbase = wk ? 4 : 0;
#pragma unroll
    for (int nt = 0; nt < 4; ++nt) {
        const int col = n0 + wn * 64 + nt * 16 + l16;
        const float bv = bias[col];
#pragma unroll
        for (int q = 0; q < 4; ++q) {
            const int mt = mbase + q;
#pragma unroll
            for (int r = 0; r < 4; ++r) {
                const int row = m0 + wm * 128 + mt * 16 + quad * 4 + r;
                out[(size_t)row * Ndim + col] = acc[mt][nt][r] + bv;
            }
        }
    }
}

// ---------------------------------------------------------------------------
// Fused fallback (round-0 verified kernel) for small workspace.
// ---------------------------------------------------------------------------
template <bool PRE>
__global__ __launch_bounds__(256, 3)
void qgemm_kernel(const float* __restrict__ x,
                  const bf16_t* __restrict__ xb,
                  const uint* __restrict__ qweight,
                  const uint* __restrict__ qzeros,
                  const float* __restrict__ scales,
                  const float* __restrict__ bias,
                  float* __restrict__ out)
{
    __shared__ bf16_t As[BM * SA];
    __shared__ bf16_t Bs[BN * SB];
    __shared__ uint   qbuf[16 * SQ];

    const int t  = threadIdx.x;
    const int m0 = blockIdx.y * BM;
    const int n0 = blockIdx.x * BN;
    const int c0 = n0 >> 3;

    const int wave = t >> 6;
    const int lane = t & 63;
    const int quad = lane >> 4;
    const int l16  = lane & 15;
    const int mw = (wave >> 1) * 64;
    const int nw = (wave & 1) * 64;

    floatx4 acc[4][4];
#pragma unroll
    for (int i = 0; i < 4; ++i)
#pragma unroll
        for (int j = 0; j < 4; ++j)
            acc[i][j] = (floatx4){0.f, 0.f, 0.f, 0.f};

    const int am = t >> 3;
    const int ao = t & 7;
    const int qk  = t >> 2;
    const int qc4 = (t & 3) * 4;
    const int nloc  = t & 127;
    const int khalf = t >> 7;
    const int cc    = nloc >> 3;
    const int jsh   = (nloc & 7) * 4;

    for (int kt = 0; kt < Kdim / BK; ++kt) {
        const int k0 = kt * BK;
        const int g  = k0 >> 7;

#pragma unroll
        for (int p = 0; p < 4; ++p) {
            const int m = p * 32 + am;
            if (PRE) {
                const bf16x8 v = *(const bf16x8*)(xb + (size_t)(m0 + m) * Kdim + k0 + ao * 8);
                *(bf16x8*)&As[m * SA + ao * 8] = v;
            } else {
                const float* src = x + (size_t)(m0 + m) * Kdim + k0 + ao * 8;
                const float4 a = *(const float4*)src;
                const float4 b = *(const float4*)(src + 4);
                bf16x8 v;
                v[0] = (bf16_t)a.x; v[1] = (bf16_t)a.y; v[2] = (bf16_t)a.z; v[3] = (bf16_t)a.w;
                v[4] = (bf16_t)b.x; v[5] = (bf16_t)b.y; v[6] = (bf16_t)b.z; v[7] = (bf16_t)b.w;
                *(bf16x8*)&As[m * SA + ao * 8] = v;
            }
        }
        {
            const uint4 w4 = *(const uint4*)(qweight + (size_t)(k0 + qk) * NPK + c0 + qc4);
            qbuf[(qc4 + 0) * SQ + qk] = w4.x;
            qbuf[(qc4 + 1) * SQ + qk] = w4.y;
            qbuf[(qc4 + 2) * SQ + qk] = w4.z;
            qbuf[(qc4 + 3) * SQ + qk] = w4.w;
        }
        __syncthreads();

        {
            const uint  zw = qzeros[(size_t)g * NPK + c0 + cc];
            const float s  = scales[(size_t)g * Ndim + n0 + nloc];
            const float zs = (float)((zw >> jsh) & 15u) * s;
            const uint* qrow = &qbuf[cc * SQ + khalf * 32];
#pragma unroll
            for (int j = 0; j < 4; ++j) {
                const uint4 qa = *(const uint4*)(qrow + j * 8);
                const uint4 qb = *(const uint4*)(qrow + j * 8 + 4);
                bf16x8 v;
                v[0] = (bf16_t)((float)((qa.x >> jsh) & 15u) * s - zs);
                v[1] = (bf16_t)((float)((qa.y >> jsh) & 15u) * s - zs);
                v[2] = (bf16_t)((float)((qa.z >> jsh) & 15u) * s - zs);
                v[3] = (bf16_t)((float)((qa.w >> jsh) & 15u) * s - zs);
                v[4] = (bf16_t)((float)((qb.x >> jsh) & 15u) * s - zs);
                v[5] = (bf16_t)((float)((qb.y >> jsh) & 15u) * s - zs);
                v[6] = (bf16_t)((float)((qb.z >> jsh) & 15u) * s - zs);
                v[7] = (bf16_t)((float)((qb.w >> jsh) & 15u) * s - zs);
                *(bf16x8*)&Bs[nloc * SB + khalf * 32 + j * 8] = v;
            }
        }
        __syncthreads();

#pragma unroll
        for (int s = 0; s < 2; ++s) {
            bf16x8 fa[4], fb[4];
#pragma unroll
            for (int mt = 0; mt < 4; ++mt)
                fa[mt] = *(const bf16x8*)&As[(mw + mt * 16 + l16) * SA + s * 32 + quad * 8];
#pragma unroll
            for (int nt = 0; nt < 4; ++nt)
                fb[nt] = *(const bf16x8*)&Bs[(nw + nt * 16 + l16) * SB + s * 32 + quad * 8];
#pragma unroll
            for (int mt = 0; mt < 4; ++mt)
#pragma unroll
                for (int nt = 0; nt < 4; ++nt)
                    acc[mt][nt] = MFMA(fa[mt], fb[nt], acc[mt][nt]);
        }
        __syncthreads();
    }

#pragma unroll
    for (int nt = 0; nt < 4; ++nt) {
        const int col = n0 + nw + nt * 16 + l16;
        const float b = bias[col];
#pragma unroll
        for (int mt = 0; mt < 4; ++mt) {
#pragma unroll
            for (int r = 0; r < 4; ++r) {
                const int row = m0 + mw + mt * 16 + quad * 4 + r;
                out[(size_t)row * Ndim + col] = acc[mt][nt][r] + b;
            }
        }
    }
}

extern "C" void kernel_launch(void* const* d_in, const int* in_sizes, int n_in,
                              void* d_out, int out_size, void* d_ws, size_t ws_size,
                              hipStream_t stream)
{
    const float* x        = (const float*)d_in[0];
    const uint*  qweight  = (const uint*)d_in[1];
    const uint*  qzeros   = (const uint*)d_in[2];
    const float* scales   = (const float*)d_in[3];
    const float* bias     = (const float*)d_in[4];
    float*       out      = (float*)d_out;

    const size_t wb_bytes = (size_t)Kdim * Ndim * sizeof(bf16_t);   // 90.2 MB
    const size_t xb_bytes = (size_t)Mdim * Kdim * sizeof(bf16_t);   // 16.8 MB

    if (ws_size >= wb_bytes + xb_bytes) {
        // pre-dequant + phased GEMM path
        bf16_t* wt = (bf16_t*)d_ws;
        bf16_t* xbuf = (bf16_t*)((char*)d_ws + wb_bytes);
        wdeq_kernel<<<dim3(Ndim / 128, Kdim / 64), 256, 0, stream>>>(qweight, qzeros, scales, wt);
        xcast_kernel<<<(Mdim * Kdim) / (256 * 8), 256, 0, stream>>>(x, xbuf);
        gemm8_kernel<<<dim3(86, 8), dim3(512), 0, stream>>>(xbuf, wt, bias, out);
    } else {
        // fused fallback
        bf16_t* xbuf = (bf16_t*)d_ws;
        dim3 ggrid(Ndim / BN, Mdim / BM);
        if (ws_size >= xb_bytes) {
            xcast_kernel<<<(Mdim * Kdim) / (256 * 8), 256, 0, stream>>>(x, xbuf);
            qgemm_kernel<true><<<ggrid, dim3(256), 0, stream>>>(x, xbuf, qweight, qzeros, scales, bias, out);
        } else {
            qgemm_kernel<false><<<ggrid, dim3(256), 0, stream>>>(x, xbuf, qweight, qzeros, scales, bias, out);
        }
    }
}

// Round 4
// 363.413 us; speedup vs baseline: 1.4091x; 1.4091x over previous
//
#include <hip/hip_runtime.h>

typedef __bf16 bf16_t;
typedef bf16_t bf16x8 __attribute__((ext_vector_type(8)));
typedef float  floatx4 __attribute__((ext_vector_type(4)));
typedef unsigned int uint;

constexpr int Mdim = 2048;
constexpr int Kdim = 4096;
constexpr int Ndim = 11008;
constexpr int NPK  = Ndim / 8;     // 1376 packed words per k-row
constexpr int SQ   = 68;           // qbuf stride (words)
// fused-fallback tile params
constexpr int BM = 128, BN = 128, BK = 64;
constexpr int SA = 72, SB = 72;

#define GLOAD_LDS16(g, l) \
    __builtin_amdgcn_global_load_lds((const __attribute__((address_space(1))) void*)(g), \
                                     (__attribute__((address_space(3))) void*)(l), 16, 0, 0)
#define MFMA(a, b, c) __builtin_amdgcn_mfma_f32_16x16x32_bf16((a), (b), (c), 0, 0, 0)
#define BAR()    __builtin_amdgcn_s_barrier()
#define LGKM0()  asm volatile("s_waitcnt lgkmcnt(0)" ::: "memory")
#define VMCNT2() asm volatile("s_waitcnt vmcnt(2)" ::: "memory")
#define PRIO1()  __builtin_amdgcn_s_setprio(1)
#define PRIO0()  __builtin_amdgcn_s_setprio(0)

__global__ void xcast_kernel(const float* __restrict__ x, bf16_t* __restrict__ xb)
{
    const int i = (blockIdx.x * 256 + threadIdx.x) * 8;
    const float4 a = *(const float4*)(x + i);
    const float4 b = *(const float4*)(x + i + 4);
    bf16x8 v;
    v[0] = (bf16_t)a.x; v[1] = (bf16_t)a.y; v[2] = (bf16_t)a.z; v[3] = (bf16_t)a.w;
    v[4] = (bf16_t)b.x; v[5] = (bf16_t)b.y; v[6] = (bf16_t)b.z; v[7] = (bf16_t)b.w;
    *(bf16x8*)(xb + i) = v;
}

// ---------------------------------------------------------------------------
// One-shot W dequant: qweight [k][c] int4-packed -> wt [n][k] bf16 (W^T).
// Write-coalesced: 8 consecutive lanes cover one row's 64 k (128 B contiguous
// per 8 lanes). qbuf reads are wave-broadcast (same cc per wave).
// ---------------------------------------------------------------------------
__global__ __launch_bounds__(256, 4)
void wdeq_kernel(const uint* __restrict__ qweight, const uint* __restrict__ qzeros,
                 const float* __restrict__ scales, bf16_t* __restrict__ wt)
{
    __shared__ uint qbuf[16 * SQ];
    const int t  = threadIdx.x;
    const int n0 = blockIdx.x * 128;
    const int k0 = blockIdx.y * 64;
    const int c0 = n0 >> 3;
    const int g  = k0 >> 7;

    const int qk  = t >> 2;
    const int qc4 = (t & 3) * 4;
    const uint4 w4 = *(const uint4*)(qweight + (size_t)(k0 + qk) * NPK + c0 + qc4);
    qbuf[(qc4 + 0) * SQ + qk] = w4.x;
    qbuf[(qc4 + 1) * SQ + qk] = w4.y;
    qbuf[(qc4 + 2) * SQ + qk] = w4.z;
    qbuf[(qc4 + 3) * SQ + qk] = w4.w;
    __syncthreads();

    const int kcol = t & 7;            // k-word block
    const int nr   = t >> 3;           // 0..31
    const int jsh  = (nr & 7) * 4;     // invariant across j (row += 32)
#pragma unroll
    for (int j = 0; j < 4; ++j) {
        const int row = nr + j * 32;          // 0..127
        const int cc  = row >> 3;             // 0..15
        const uint  zw = qzeros[(size_t)g * NPK + c0 + cc];
        const float s  = scales[(size_t)g * Ndim + n0 + row];
        const float zs = (float)((zw >> jsh) & 15u) * s;
        const uint* qrow = &qbuf[cc * SQ + kcol * 8];
        const uint4 qa = *(const uint4*)(qrow);
        const uint4 qb = *(const uint4*)(qrow + 4);
        bf16x8 v;
        v[0] = (bf16_t)((float)((qa.x >> jsh) & 15u) * s - zs);
        v[1] = (bf16_t)((float)((qa.y >> jsh) & 15u) * s - zs);
        v[2] = (bf16_t)((float)((qa.z >> jsh) & 15u) * s - zs);
        v[3] = (bf16_t)((float)((qa.w >> jsh) & 15u) * s - zs);
        v[4] = (bf16_t)((float)((qb.x >> jsh) & 15u) * s - zs);
        v[5] = (bf16_t)((float)((qb.y >> jsh) & 15u) * s - zs);
        v[6] = (bf16_t)((float)((qb.z >> jsh) & 15u) * s - zs);
        v[7] = (bf16_t)((float)((qb.w >> jsh) & 15u) * s - zs);
        *(bf16x8*)(wt + (size_t)(n0 + row) * Kdim + k0 + kcol * 8) = v;
    }
}

// ---------------------------------------------------------------------------
// Phased bf16 GEMM with K-SPLIT waves.
// BM=256, BN=128, BK=64. 512 threads = 8 waves as 2M x 2N x 2K.
// Wave tile 128(m) x 64(n) on k-slice wk.
// EPILOGUE NOTE (round-3 lesson, rule #20): wk-dependent acc indices MUST be
// compile-time -> uniform branch on wk with static indices in each arm;
// barriers stay outside the branches.
// ---------------------------------------------------------------------------
__global__ __launch_bounds__(512, 2)
void gemm8_kernel(const bf16_t* __restrict__ xb, const bf16_t* __restrict__ wt,
                  const float* __restrict__ bias, float* __restrict__ out)
{
    __shared__ bf16_t As[2 * 16384];   // 64 KiB  [p][h][128][64]
    __shared__ bf16_t Bs[2 * 8192];    // 32 KiB  [p][128][64]

    const int t    = threadIdx.x;
    const int w    = t >> 6;
    const int lane = t & 63;
    const int quad = lane >> 4;
    const int l16  = lane & 15;
    const int wm   = w >> 2;           // 0..1  (m half)
    const int wn   = (w >> 1) & 1;     // 0..1  (n half)
    const int wk   = w & 1;            // 0..1  (k slice)
    const int w64  = w * 64;

    // T1: XCD-aware remap (688 = 8*86, bijective).
    const int flat = blockIdx.y * 86 + blockIdx.x;
    const int nf   = (flat & 7) * 86 + (flat >> 3);
    const int m0   = (nf / 86) * 256;
    const int n0   = (nf % 86) * 128;

    auto stageA = [&](int T, int h) {
        const int p  = T & 1;
        const int Tk = (T & 63) * 64;
#pragma unroll
        for (int l = 0; l < 2; ++l) {
            const int idx = l * 512 + w64 + lane;
            const int r   = idx >> 3;
            const int bc  = (idx & 7) ^ (r & 7);
            GLOAD_LDS16(xb + (size_t)(m0 + h * 128 + r) * Kdim + Tk + bc * 8,
                        As + (p * 16384 + h * 8192 + (l * 512 + w64) * 8));
        }
    };
    auto stageB = [&](int T) {
        const int p  = T & 1;
        const int Tk = (T & 63) * 64;
#pragma unroll
        for (int l = 0; l < 2; ++l) {
            const int idx = l * 512 + w64 + lane;
            const int r   = idx >> 3;
            const int bc  = (idx & 7) ^ (r & 7);
            GLOAD_LDS16(wt + (size_t)(n0 + r) * Kdim + Tk + bc * 8,
                        Bs + (p * 8192 + (l * 512 + w64) * 8));
        }
    };
    auto lda = [&](int p, int mt) -> bf16x8 {
        const int r = mt * 16 + l16;
        return *(const bf16x8*)(As + p * 16384 + wm * 8192 + r * 64 +
                                ((wk * 4 + quad) ^ (l16 & 7)) * 8);
    };
    auto ldb = [&](int p, int nt) -> bf16x8 {
        const int r = wn * 64 + nt * 16 + l16;
        return *(const bf16x8*)(Bs + p * 8192 + r * 64 +
                                ((wk * 4 + quad) ^ (l16 & 7)) * 8);
    };

    floatx4 acc[8][4];
#pragma unroll
    for (int i = 0; i < 8; ++i)
#pragma unroll
        for (int j = 0; j < 4; ++j)
            acc[i][j] = (floatx4){0.f, 0.f, 0.f, 0.f};

    // prologue: tile0 A+B, tile1 B; leave tile1's B (newest 2) outstanding
    stageA(0, 0); stageA(0, 1); stageB(0); stageB(1);
    VMCNT2(); BAR();

    bf16x8 av[4], bb[4];

#define MFMA16(G)                                                              \
    PRIO1();                                                                   \
    _Pragma("unroll") for (int mt = 0; mt < 4; ++mt)                           \
        _Pragma("unroll") for (int nt = 0; nt < 4; ++nt)                       \
            acc[(G)*4 + mt][nt] = MFMA(av[mt], bb[nt], acc[(G)*4 + mt][nt]);   \
    PRIO0();

    for (int i = 0; i < 32; ++i) {
        // ---- phase 1: buf0, m-frags 0-3 ----
        bb[0] = ldb(0, 0); bb[1] = ldb(0, 1); bb[2] = ldb(0, 2); bb[3] = ldb(0, 3);
        av[0] = lda(0, 0); av[1] = lda(0, 1); av[2] = lda(0, 2); av[3] = lda(0, 3);
        stageA(2 * i + 1, 0); stageA(2 * i + 1, 1);
        BAR(); LGKM0();
        MFMA16(0);
        BAR();

        // ---- phase 2: buf0, m-frags 4-7 (bb reused) ----
        av[0] = lda(0, 4); av[1] = lda(0, 5); av[2] = lda(0, 6); av[3] = lda(0, 7);
        stageB(2 * i + 2);
        VMCNT2();
        BAR(); LGKM0();
        MFMA16(1);
        BAR();

        // ---- phase 3: buf1, m-frags 0-3 ----
        bb[0] = ldb(1, 0); bb[1] = ldb(1, 1); bb[2] = ldb(1, 2); bb[3] = ldb(1, 3);
        av[0] = lda(1, 0); av[1] = lda(1, 1); av[2] = lda(1, 2); av[3] = lda(1, 3);
        stageA(2 * i + 2, 0); stageA(2 * i + 2, 1);
        BAR(); LGKM0();
        MFMA16(0);
        BAR();

        // ---- phase 4: buf1, m-frags 4-7 ----
        av[0] = lda(1, 4); av[1] = lda(1, 5); av[2] = lda(1, 6); av[3] = lda(1, 7);
        stageB(2 * i + 3);
        VMCNT2();
        BAR(); LGKM0();
        MFMA16(1);
        BAR();
    }
#undef MFMA16

    // ---- cross-k reduction: partner wave = w^1 (same wm,wn, other wk).
    // wk0 keeps m-frags 0-3 (sends 4-7); wk1 keeps 4-7 (sends 0-3).
    // All acc indices compile-time (uniform branch on wk); barriers uniform.
    // Outstanding tail stages target Bs only, so As is safe as exchange buf.
    {
        float* exf = (float*)As;           // 8 waves * 2048 floats = 64 KiB
        const int pw = w ^ 1;
#pragma unroll
        for (int c = 0; c < 2; ++c) {
            if (wk == 0) {
#pragma unroll
                for (int q = 0; q < 2; ++q)
#pragma unroll
                    for (int nt = 0; nt < 4; ++nt)
                        *(floatx4*)(exf + w * 2048 + ((q * 4 + nt) * 64 + lane) * 4) =
                            acc[4 + c * 2 + q][nt];
            } else {
#pragma unroll
                for (int q = 0; q < 2; ++q)
#pragma unroll
                    for (int nt = 0; nt < 4; ++nt)
                        *(floatx4*)(exf + w * 2048 + ((q * 4 + nt) * 64 + lane) * 4) =
                            acc[c * 2 + q][nt];
            }
            __syncthreads();
            if (wk == 0) {
#pragma unroll
                for (int q = 0; q < 2; ++q)
#pragma unroll
                    for (int nt = 0; nt < 4; ++nt)
                        acc[c * 2 + q][nt] += *(const floatx4*)(exf + pw * 2048 +
                                                ((q * 4 + nt) * 64 + lane) * 4);
            } else {
#pragma unroll
                for (int q = 0; q < 2; ++q)
#pragma unroll
                    for (int nt = 0; nt < 4; ++nt)
                        acc[4 + c * 2 + q][nt] += *(const floatx4*)(exf + pw * 2048 +
                                                ((q * 4 + nt) * 64 + lane) * 4);
            }
            __syncthreads();
        }
    }

    // ---- store: wk0 stores m-frags 0-3, wk1 stores 4-7 (static indices) ----
    if (wk == 0) {
#pragma unroll
        for (int nt = 0; nt < 4; ++nt) {
            const int col = n0 + wn * 64 + nt * 16 + l16;
            const float bv = bias[col];
#pragma unroll
            for (int q = 0; q < 4; ++q)
#pragma unroll
                for (int r = 0; r < 4; ++r) {
                    const int row = m0 + wm * 128 + q * 16 + quad * 4 + r;
                    out[(size_t)row * Ndim + col] = acc[q][nt][r] + bv;
                }
        }
    } else {
#pragma unroll
        for (int nt = 0; nt < 4; ++nt) {
            const int col = n0 + wn * 64 + nt * 16 + l16;
            const float bv = bias[col];
#pragma unroll
            for (int q = 0; q < 4; ++q)
#pragma unroll
                for (int r = 0; r < 4; ++r) {
                    const int row = m0 + wm * 128 + (4 + q) * 16 + quad * 4 + r;
                    out[(size_t)row * Ndim + col] = acc[4 + q][nt][r] + bv;
                }
        }
    }
}

// ---------------------------------------------------------------------------
// Fused fallback (round-0 verified kernel) for small workspace.
// ---------------------------------------------------------------------------
template <bool PRE>
__global__ __launch_bounds__(256, 3)
void qgemm_kernel(const float* __restrict__ x,
                  const bf16_t* __restrict__ xb,
                  const uint* __restrict__ qweight,
                  const uint* __restrict__ qzeros,
                  const float* __restrict__ scales,
                  const float* __restrict__ bias,
                  float* __restrict__ out)
{
    __shared__ bf16_t As[BM * SA];
    __shared__ bf16_t Bs[BN * SB];
    __shared__ uint   qbuf[16 * SQ];

    const int t  = threadIdx.x;
    const int m0 = blockIdx.y * BM;
    const int n0 = blockIdx.x * BN;
    const int c0 = n0 >> 3;

    const int wave = t >> 6;
    const int lane = t & 63;
    const int quad = lane >> 4;
    const int l16  = lane & 15;
    const int mw = (wave >> 1) * 64;
    const int nw = (wave & 1) * 64;

    floatx4 acc[4][4];
#pragma unroll
    for (int i = 0; i < 4; ++i)
#pragma unroll
        for (int j = 0; j < 4; ++j)
            acc[i][j] = (floatx4){0.f, 0.f, 0.f, 0.f};

    const int am = t >> 3;
    const int ao = t & 7;
    const int qk  = t >> 2;
    const int qc4 = (t & 3) * 4;
    const int nloc  = t & 127;
    const int khalf = t >> 7;
    const int cc    = nloc >> 3;
    const int jsh   = (nloc & 7) * 4;

    for (int kt = 0; kt < Kdim / BK; ++kt) {
        const int k0 = kt * BK;
        const int g  = k0 >> 7;

#pragma unroll
        for (int p = 0; p < 4; ++p) {
            const int m = p * 32 + am;
            if (PRE) {
                const bf16x8 v = *(const bf16x8*)(xb + (size_t)(m0 + m) * Kdim + k0 + ao * 8);
                *(bf16x8*)&As[m * SA + ao * 8] = v;
            } else {
                const float* src = x + (size_t)(m0 + m) * Kdim + k0 + ao * 8;
                const float4 a = *(const float4*)src;
                const float4 b = *(const float4*)(src + 4);
                bf16x8 v;
                v[0] = (bf16_t)a.x; v[1] = (bf16_t)a.y; v[2] = (bf16_t)a.z; v[3] = (bf16_t)a.w;
                v[4] = (bf16_t)b.x; v[5] = (bf16_t)b.y; v[6] = (bf16_t)b.z; v[7] = (bf16_t)b.w;
                *(bf16x8*)&As[m * SA + ao * 8] = v;
            }
        }
        {
            const uint4 w4 = *(const uint4*)(qweight + (size_t)(k0 + qk) * NPK + c0 + qc4);
            qbuf[(qc4 + 0) * SQ + qk] = w4.x;
            qbuf[(qc4 + 1) * SQ + qk] = w4.y;
            qbuf[(qc4 + 2) * SQ + qk] = w4.z;
            qbuf[(qc4 + 3) * SQ + qk] = w4.w;
        }
        __syncthreads();

        {
            const uint  zw = qzeros[(size_t)g * NPK + c0 + cc];
            const float s  = scales[(size_t)g * Ndim + n0 + nloc];
            const float zs = (float)((zw >> jsh) & 15u) * s;
            const uint* qrow = &qbuf[cc * SQ + khalf * 32];
#pragma unroll
            for (int j = 0; j < 4; ++j) {
                const uint4 qa = *(const uint4*)(qrow + j * 8);
                const uint4 qb = *(const uint4*)(qrow + j * 8 + 4);
                bf16x8 v;
                v[0] = (bf16_t)((float)((qa.x >> jsh) & 15u) * s - zs);
                v[1] = (bf16_t)((float)((qa.y >> jsh) & 15u) * s - zs);
                v[2] = (bf16_t)((float)((qa.z >> jsh) & 15u) * s - zs);
                v[3] = (bf16_t)((float)((qa.w >> jsh) & 15u) * s - zs);
                v[4] = (bf16_t)((float)((qb.x >> jsh) & 15u) * s - zs);
                v[5] = (bf16_t)((float)((qb.y >> jsh) & 15u) * s - zs);
                v[6] = (bf16_t)((float)((qb.z >> jsh) & 15u) * s - zs);
                v[7] = (bf16_t)((float)((qb.w >> jsh) & 15u) * s - zs);
                *(bf16x8*)&Bs[nloc * SB + khalf * 32 + j * 8] = v;
            }
        }
        __syncthreads();

#pragma unroll
        for (int s = 0; s < 2; ++s) {
            bf16x8 fa[4], fb[4];
#pragma unroll
            for (int mt = 0; mt < 4; ++mt)
                fa[mt] = *(const bf16x8*)&As[(mw + mt * 16 + l16) * SA + s * 32 + quad * 8];
#pragma unroll
            for (int nt = 0; nt < 4; ++nt)
                fb[nt] = *(const bf16x8*)&Bs[(nw + nt * 16 + l16) * SB + s * 32 + quad * 8];
#pragma unroll
            for (int mt = 0; mt < 4; ++mt)
#pragma unroll
                for (int nt = 0; nt < 4; ++nt)
                    acc[mt][nt] = MFMA(fa[mt], fb[nt], acc[mt][nt]);
        }
        __syncthreads();
    }

#pragma unroll
    for (int nt = 0; nt < 4; ++nt) {
        const int col = n0 + nw + nt * 16 + l16;
        const float b = bias[col];
#pragma unroll
        for (int mt = 0; mt < 4; ++mt) {
#pragma unroll
            for (int r = 0; r < 4; ++r) {
                const int row = m0 + mw + mt * 16 + quad * 4 + r;
                out[(size_t)row * Ndim + col] = acc[mt][nt][r] + b;
            }
        }
    }
}

extern "C" void kernel_launch(void* const* d_in, const int* in_sizes, int n_in,
                              void* d_out, int out_size, void* d_ws, size_t ws_size,
                              hipStream_t stream)
{
    const float* x        = (const float*)d_in[0];
    const uint*  qweight  = (const uint*)d_in[1];
    const uint*  qzeros   = (const uint*)d_in[2];
    const float* scales   = (const float*)d_in[3];
    const float* bias     = (const float*)d_in[4];
    float*       out      = (float*)d_out;

    const size_t wb_bytes = (size_t)Kdim * Ndim * sizeof(bf16_t);   // 90.2 MB
    const size_t xb_bytes = (size_t)Mdim * Kdim * sizeof(bf16_t);   // 16.8 MB

    if (ws_size >= wb_bytes + xb_bytes) {
        // pre-dequant + phased GEMM path
        bf16_t* wt = (bf16_t*)d_ws;
        bf16_t* xbuf = (bf16_t*)((char*)d_ws + wb_bytes);
        wdeq_kernel<<<dim3(Ndim / 128, Kdim / 64), 256, 0, stream>>>(qweight, qzeros, scales, wt);
        xcast_kernel<<<(Mdim * Kdim) / (256 * 8), 256, 0, stream>>>(x, xbuf);
        gemm8_kernel<<<dim3(86, 8), dim3(512), 0, stream>>>(xbuf, wt, bias, out);
    } else {
        // fused fallback
        bf16_t* xbuf = (bf16_t*)d_ws;
        dim3 ggrid(Ndim / BN, Mdim / BM);
        if (ws_size >= xb_bytes) {
            xcast_kernel<<<(Mdim * Kdim) / (256 * 8), 256, 0, stream>>>(x, xbuf);
            qgemm_kernel<true><<<ggrid, dim3(256), 0, stream>>>(x, xbuf, qweight, qzeros, scales, bias, out);
        } else {
            qgemm_kernel<false><<<ggrid, dim3(256), 0, stream>>>(x, xbuf, qweight, qzeros, scales, bias, out);
        }
    }
}